// Round 3
// baseline (62.950 us; speedup 1.0000x reference)
//
#include <hip/hip_runtime.h>

// SConv2d with MAJ3 tree reduction.
// x: (8, 27, 32, 32) f32, w: (27, 27, 3, 3) f32 -> out: (8, 27, 32, 32) f32.
// s-domain trick: (x+1)/2 ... 2r-1 cancels between tree levels; convert once
// at the leaves (s = (0.5*x)*w + 0.5, x prescaled) and once at the root.
//
// R9: structural rework. Evidence: R7 (-30% VALU issue) = null, R8 (staging
// vectorize + setprio) = -1.2 us => kernel phase is structure/latency-bound,
// not pipe-bound. Old shape (448 blocks x 12 waves, cross-wave c3 split):
//   - 7 ocg-blocks per (n,rg) each stage the SAME 20.7 KB tile (9.3 MB total)
//   - 448 blocks / 256 CUs with 2-resident cap => 64 CUs half-idle
//   - c3 partials live in different waves => part[] LDS round-trip + 2nd barrier
// New shape: grid 8n x 4ocg x 8rg = 256 blocks (exactly 1/CU), 7 waves x 64
// (448 thr), wave = one oc (groups 7,7,7,6), thread = 2 adjacent px with the
// FULL 27-channel tree in-thread (c3 level in-registers). Same association
// order (kw, kh, c1, c2, c3) => bit-identical numerics. Staged bytes halve,
// phase 3 + part[] + one barrier deleted, output stored directly (8B/lane).
// Packed v2f ops over the two pixel streams kept from R7.

#define HH 32
#define WW 32
#define CC 27
#define OCC 27

typedef float v2f __attribute__((ext_vector_type(2)));

__device__ __forceinline__ v2f splat2(float s) { v2f r; r.x = s; r.y = s; return r; }

// majority gate on s-domain values: ab + ac + bc - 2abc, packed over the
// two pixel streams (v_pk_mul + v_pk_add + 2x v_pk_fma).
__device__ __forceinline__ v2f maj3v(v2f a, v2f b, v2f c) {
    v2f ab = a * b;
    v2f t  = __builtin_elementwise_fma(splat2(-2.0f), ab, a + b);  // a+b-2ab
    return __builtin_elementwise_fma(c, t, ab);                    // ab + c*t
}

// tile: 27 ch x 6 rows x stride 36 floats (23.3 KB), prescaled 0.5, pad -0.5.
__global__ __launch_bounds__(448) void sconv_maj_kernel(
    const float* __restrict__ x, const float* __restrict__ w, float* __restrict__ out)
{
    __shared__ float tile[27 * 6 * 36];   // 23,328 B

    const int b   = blockIdx.x;
    const int rg  = b & 7;            // 8 row-groups of 4 output rows
    const int ocg = (b >> 3) & 3;     // 4 groups of 7 oc (last has 6)
    const int n   = b >> 5;
    const int tid = threadIdx.x;

    const float* __restrict__ xb = x + n * (CC * HH * WW);

    // ---- stage prescaled, padded tile: 162 rows x 8 float4-quads ----
    // slot s in [0,1296): R = s>>3 (row = c*6+tr), q = s&7 (cols 4q..4q+3)
#pragma unroll
    for (int it = 0; it < 3; ++it) {
        const int s = tid + it * 448;
        if (s < 162 * 8) {
            const int R  = s >> 3;
            const int q  = s & 7;
            const int c  = R / 6;
            const int tr = R - c * 6;
            const int ih = rg * 4 + tr - 1;
            float4 v = make_float4(-0.5f, -0.5f, -0.5f, -0.5f);
            if ((unsigned)ih < 32u) {
                const float4 u = *(const float4*)(xb + c * (HH * WW) + ih * WW + q * 4);
                v.x = 0.5f * u.x; v.y = 0.5f * u.y;
                v.z = 0.5f * u.z; v.w = 0.5f * u.w;
            }
            float* d = &tile[R * 36 + 1 + q * 4];
            d[0] = v.x; d[1] = v.y; d[2] = v.z; d[3] = v.w;
        }
    }
    if (tid < 324) {                               // col 0 and col 33 borders
        const int R = tid >> 1;
        tile[R * 36 + ((tid & 1) ? 33 : 0)] = -0.5f;
    }
    __syncthreads();

    // ---- full tree: wave = oc; thread = 2 adjacent px, all 27 channels ----
    const int wavei = __builtin_amdgcn_readfirstlane(tid >> 6);  // 0..6, SGPR
    const int oc    = ocg * 7 + wavei;             // scalar -> s_load weights
    const int lt  = tid & 63;
    const int pr  = lt >> 4;           // local pixel row 0..3
    const int ow0 = (lt & 15) << 1;    // even column pair ow0, ow0+1

    if (oc < OCC) {
        const float* __restrict__ wp = w + oc * 243;   // all 27 channels

        v2f l5[3];
#pragma unroll
        for (int c3 = 0; c3 < 3; ++c3) {
            v2f l4[3];
#pragma unroll
            for (int c2 = 0; c2 < 3; ++c2) {
                v2f l3[3];
#pragma unroll
                for (int c1 = 0; c1 < 3; ++c1) {
                    const int c = c3 * 9 + c2 * 3 + c1;    // absolute channel
                    const float* trow = &tile[(c * 6 + pr) * 36 + ow0];
                    v2f rv[3];
#pragma unroll
                    for (int kh = 0; kh < 3; ++kh) {
                        // taps ow0..ow0+3 (8B-aligned pairs)
                        const float2 u0 = *(const float2*)(trow + kh * 36);
                        const float2 u1 = *(const float2*)(trow + kh * 36 + 2);
                        const float w0 = wp[c * 9 + kh * 3 + 0];
                        const float w1 = wp[c * 9 + kh * 3 + 1];
                        const float w2 = wp[c * 9 + kh * 3 + 2];
                        // pixel-pair tap vectors: lane0 = px ow0, lane1 = px ow0+1
                        v2f t0; t0.x = u0.x; t0.y = u0.y;
                        v2f t1; t1.x = u0.y; t1.y = u1.x;
                        v2f t2; t2.x = u1.x; t2.y = u1.y;
                        // leaf: s = (x*w+1)/2 = (0.5x)*w + 0.5; level 1: kw
                        v2f s0 = __builtin_elementwise_fma(t0, splat2(w0), splat2(0.5f));
                        v2f s1 = __builtin_elementwise_fma(t1, splat2(w1), splat2(0.5f));
                        v2f s2 = __builtin_elementwise_fma(t2, splat2(w2), splat2(0.5f));
                        rv[kh] = maj3v(s0, s1, s2);
                    }
                    l3[c1] = maj3v(rv[0], rv[1], rv[2]);   // level 2: kh
                }
                l4[c2] = maj3v(l3[0], l3[1], l3[2]);       // level 3: c1
            }
            l5[c3] = maj3v(l4[0], l4[1], l4[2]);           // level 4: c2
        }
        const v2f f = maj3v(l5[0], l5[1], l5[2]);          // level 5: c3
        // back-convert: y = 2r - 1
        const v2f y = __builtin_elementwise_fma(splat2(2.0f), f, splat2(-1.0f));

        const int oh = rg * 4 + pr;
        float* op = out + (((n * OCC + oc) * HH) + oh) * WW + ow0;
        *(float2*)op = make_float2(y.x, y.y);              // coalesced 8B/lane
    }
}

extern "C" void kernel_launch(void* const* d_in, const int* in_sizes, int n_in,
                              void* d_out, int out_size, void* d_ws, size_t ws_size,
                              hipStream_t stream) {
    const float* x = (const float*)d_in[0];
    const float* w = (const float*)d_in[1];
    float* out = (float*)d_out;
    // grid: 8 n * 4 oc-groups * 8 row-groups = 256 blocks (1 per CU),
    // 448 threads (7 waves; wave = one output channel)
    sconv_maj_kernel<<<dim3(8 * 4 * 8), dim3(448), 0, stream>>>(x, w, out);
}

// Round 5
// 61.223 us; speedup vs baseline: 1.0282x; 1.0282x over previous
//
#include <hip/hip_runtime.h>

// SConv2d with MAJ3 tree reduction.
// x: (8, 27, 32, 32) f32, w: (27, 27, 3, 3) f32 -> out: (8, 27, 32, 32) f32.
// s-domain trick: (x+1)/2 ... 2r-1 cancels between tree levels; convert once
// at the leaves (s = (0.5*x)*w + 0.5, x prescaled) and once at the root.
//
// R11 = R10 resubmitted verbatim (R10's bench failed on container
// acquisition — no measurement was taken).
// R10 = R8 base (best measured 60.5 us) + ONE change: weights move from
// scalar s_load (SMEM) to an LDS stage + ds_read. Rationale: SMEM and DS
// share lgkmcnt and SMEM completes out-of-order, so the tree's 81 weight
// s_loads interleaved with 54 tile ds_reads force conservative lgkmcnt(0)
// drains (the 102-SGPR budget can't hold all weights hoisted). With weights
// in LDS the hot loop is all-DS: precisely counted lgkm waits, weight+tile
// reads batched together. Uniform-address ds_reads broadcast (no conflict).
// Evidence trail: R7 (-30% VALU) null, R8 (staging latency) -1.2 us,
// R9 (lean/low-TLP restructure) +2.4 us -> kernel is lgkm-latency-bound.
// Grid 448x768, c3-split, part[] combine, tree association: identical.

#define HH 32
#define WW 32
#define CC 27
#define OCC 27

typedef float v2f __attribute__((ext_vector_type(2)));

__device__ __forceinline__ v2f splat2(float s) { v2f r; r.x = s; r.y = s; return r; }

// majority gate on s-domain values: ab + ac + bc - 2abc, packed over the
// two pixel streams (v_pk_mul + v_pk_add + 2x v_pk_fma).
__device__ __forceinline__ v2f maj3v(v2f a, v2f b, v2f c) {
    v2f ab = a * b;
    v2f t  = __builtin_elementwise_fma(splat2(-2.0f), ab, a + b);  // a+b-2ab
    return __builtin_elementwise_fma(c, t, ab);                    // ab + c*t
}

// scalar variant for the phase-3 combine (one px/thread there)
__device__ __forceinline__ float maj3(float a, float b, float c) {
    float ab = a * b;
    float t  = fmaf(-2.0f, ab, a + b);
    return fmaf(c, t, ab);
}

// LDS: tile 27ch x 6 rows x stride 36 (23.3 KB, prescaled 0.5, pad -0.5)
//      part 4 oc x 128 px x 3 c3 (6 KB)
//      wlds 4 oc x 243 weights (3.9 KB)   -> total 33,360 B (2 blocks/CU ok)
__global__ __launch_bounds__(768) void sconv_maj_kernel(
    const float* __restrict__ x, const float* __restrict__ w, float* __restrict__ out)
{
    __shared__ float smem[27 * 6 * 36 + 4 * 128 * 3 + 4 * 243];
    float* tile = smem;
    float* part = smem + 27 * 6 * 36;
    float* wlds = smem + 27 * 6 * 36 + 4 * 128 * 3;

    const int b    = blockIdx.x;
    const int rg   = b & 7;            // 8 row-groups of 4 output rows
    const int rest = b >> 3;
    const int ocg  = rest % 7;         // 7 groups of 4 oc (last has 3)
    const int n    = rest / 7;
    const int tid  = threadIdx.x;

    const float* __restrict__ xb = x + n * (CC * HH * WW);

    // ---- stage weights for this block's oc group (<= 972 floats) ----
    {
        const int nw = (ocg == 6 ? 3 : 4) * 243;
        const float* __restrict__ wg = w + ocg * 4 * 243;
        if (tid < nw)            wlds[tid]       = wg[tid];
        const int t2 = tid + 768;
        if (t2 < nw)             wlds[t2]        = wg[t2];
    }

    // ---- stage prescaled, padded tile: 162 rows x 8 float4-quads ----
    // slot s in [0,1296): R = s>>3 (row = c*6+tr), q = s&7 (cols 4q..4q+3)
    {
#pragma unroll
        for (int it = 0; it < 2; ++it) {
            const int s = tid + it * 768;
            if (s < 162 * 8) {
                const int R  = s >> 3;
                const int q  = s & 7;
                const int c  = R / 6;
                const int tr = R - c * 6;
                const int ih = rg * 4 + tr - 1;
                float4 v = make_float4(-0.5f, -0.5f, -0.5f, -0.5f);
                if ((unsigned)ih < 32u) {
                    const float4 u = *(const float4*)(xb + c * (HH * WW) + ih * WW + q * 4);
                    v.x = 0.5f * u.x; v.y = 0.5f * u.y;
                    v.z = 0.5f * u.z; v.w = 0.5f * u.w;
                }
                float* d = &tile[R * 36 + 1 + q * 4];
                d[0] = v.x; d[1] = v.y; d[2] = v.z; d[3] = v.w;
            }
        }
        if (tid < 324) {                           // col 0 and col 33 borders
            const int R = tid >> 1;
            tile[R * 36 + ((tid & 1) ? 33 : 0)] = -0.5f;
        }
    }
    __syncthreads();

    // ---- partial trees: wave = (oc_local, c3); thread = 2 adjacent px ----
    const int wavei    = __builtin_amdgcn_readfirstlane(tid >> 6);  // 0..11, SGPR
    const int oc_local = wavei / 3;
    const int sub3     = wavei - oc_local * 3;       // c3 digit, scalar
    const int oc       = ocg * 4 + oc_local;
    const int lt  = tid & 63;
    const int pr  = lt >> 4;           // local pixel row 0..3
    const int ow0 = (lt & 15) << 1;    // even column pair ow0, ow0+1

    if (oc < OCC) {
        // weights now from LDS: uniform-address ds_reads (broadcast), same
        // lgkm domain as tile reads -> counted waits, no SMEM drains
        const float* __restrict__ wp = wlds + oc_local * 243 + sub3 * 81;

        __builtin_amdgcn_s_setprio(1);             // favor compute waves over
                                                   // the co-resident block's
                                                   // staging waves
        v2f l4[3];
#pragma unroll
        for (int c2 = 0; c2 < 3; ++c2) {
            v2f l3[3];
#pragma unroll
            for (int c1 = 0; c1 < 3; ++c1) {
                const int c  = sub3 * 9 + c2 * 3 + c1;   // absolute channel
                const int cw = c2 * 3 + c1;              // within-c3 index
                const float* trow = &tile[(c * 6 + pr) * 36 + ow0];
                v2f rv[3];
#pragma unroll
                for (int kh = 0; kh < 3; ++kh) {
                    // taps ow0..ow0+3 (8B-aligned pairs)
                    const float2 u0 = *(const float2*)(trow + kh * 36);
                    const float2 u1 = *(const float2*)(trow + kh * 36 + 2);
                    const float w0 = wp[cw * 9 + kh * 3 + 0];
                    const float w1 = wp[cw * 9 + kh * 3 + 1];
                    const float w2 = wp[cw * 9 + kh * 3 + 2];
                    // pixel-pair tap vectors: lane0 = px ow0, lane1 = px ow0+1
                    v2f t0; t0.x = u0.x; t0.y = u0.y;
                    v2f t1; t1.x = u0.y; t1.y = u1.x;
                    v2f t2; t2.x = u1.x; t2.y = u1.y;
                    // leaf: s = (x*w+1)/2 = (0.5x)*w + 0.5; then level 1: kw
                    v2f s0 = __builtin_elementwise_fma(t0, splat2(w0), splat2(0.5f));
                    v2f s1 = __builtin_elementwise_fma(t1, splat2(w1), splat2(0.5f));
                    v2f s2 = __builtin_elementwise_fma(t2, splat2(w2), splat2(0.5f));
                    rv[kh] = maj3v(s0, s1, s2);
                }
                l3[c1] = maj3v(rv[0], rv[1], rv[2]);     // level 2: kh
            }
            l4[c2] = maj3v(l3[0], l3[1], l3[2]);         // level 3: c1
        }
        const v2f pv = maj3v(l4[0], l4[1], l4[2]);       // level 4: c2 (c3-partial)
        __builtin_amdgcn_s_setprio(0);

        const int base = (oc_local * 128 + pr * 32 + ow0) * 3 + sub3;
        part[base]     = pv.x;
        part[base + 3] = pv.y;
    }
    __syncthreads();

    // ---- combine: level 5 over c3 + back-convert; 512 threads, 1 px each ----
    if (tid < 512) {
        const int ocl = tid >> 7;
        const int px  = tid & 127;
        const int oc2 = ocg * 4 + ocl;
        if (oc2 < OCC) {
            const int b0 = (ocl * 128 + px) * 3;
            const float y = fmaf(2.0f, maj3(part[b0], part[b0 + 1], part[b0 + 2]), -1.0f);
            const int oh = rg * 4 + (px >> 5);
            const int ow = px & 31;
            out[(((n * OCC + oc2) * HH) + oh) * WW + ow] = y;
        }
    }
}

extern "C" void kernel_launch(void* const* d_in, const int* in_sizes, int n_in,
                              void* d_out, int out_size, void* d_ws, size_t ws_size,
                              hipStream_t stream) {
    const float* x = (const float*)d_in[0];
    const float* w = (const float*)d_in[1];
    float* out = (float*)d_out;
    // grid: 8 n * 7 oc-groups * 8 row-groups = 448 blocks, 768 threads (12 waves)
    sconv_maj_kernel<<<dim3(8 * 7 * 8), dim3(768), 0, stream>>>(x, w, out);
}